// Round 1
// baseline (188.055 us; speedup 1.0000x reference)
//
#include <hip/hip_runtime.h>

#define NUM_LAYERS 1000
#define DIM 10
#define STRIDE 112           // floats per affine slot (10x11 = 110, padded to 112)
#define LPB 16               // layers per block in compose phase 1
#define NBLK 63              // ceil(1000/16)
#define TILE_Q4 1280         // apply: 256 threads * 5 float4 = 512 rows per tile

// Affine stored col-major in a slot: slot[j*10 + r] = M[r][j] for j<10,
// slot[100 + r] = c[r]. Compose dst = g(f(.)): col_j(dst) = M_g * col_j(f)
// (+ c_g when j==10). Lane j (0..10) owns column j.
__device__ inline void compose_one(const float* __restrict__ src,
                                   float* __restrict__ dst,
                                   int c, int lane) {
    const float* F = src + (size_t)(2 * c) * STRIDE;
    const float* G = src + (size_t)(2 * c + 1) * STRIDE;
    float colf[DIM], o[DIM];
    #pragma unroll
    for (int r = 0; r < DIM; ++r) colf[r] = F[lane * DIM + r];
    #pragma unroll
    for (int r = 0; r < DIM; ++r) {
        float acc = (lane == DIM) ? G[100 + r] : 0.f;
        #pragma unroll
        for (int k = 0; k < DIM; ++k)
            acc += G[k * DIM + r] * colf[k];
        o[r] = acc;
    }
    float* D = dst + (size_t)c * STRIDE;
    #pragma unroll
    for (int r = 0; r < DIM; ++r) D[lane * DIM + r] = o[r];
}

// ---------------------------------------------------------------------------
// Fused compose: 63 blocks each fold 16 layers (4-level LDS tree); the LAST
// block to finish (device-scope atomic counter, zeroed via hipMemsetAsync)
// folds the 63 chunk affines (6-level tree) and writes the final affine
// ROW-major: aff[r*10+k] = M[r][k], aff[100+r] = c[r].
// ---------------------------------------------------------------------------
__global__ __launch_bounds__(1024) void compose_fused(const float* __restrict__ Ws,
                                                      const float* __restrict__ bs,
                                                      float* __restrict__ wsout,
                                                      float* __restrict__ aff,
                                                      unsigned int* __restrict__ counter) {
    __shared__ float A[64 * STRIDE];   // 28.7 KB (phase1 uses 16 slots; phase2 all 64)
    __shared__ float B[32 * STRIDE];   // 14.3 KB
    __shared__ unsigned int s_last;
    const int tid = threadIdx.x;
    const int blk = blockIdx.x;

    // ---- phase 1: this block's 16 layers -> one chunk affine ----
    for (int e = tid; e < LPB * 100; e += 1024) {
        int ll = e / 100, rem = e % 100;      // rem = r*10 + k
        int r = rem / 10, k = rem % 10;
        int l = blk * LPB + ll;
        float v = (l < NUM_LAYERS) ? Ws[(size_t)l * 100 + rem]
                                   : (r == k ? 1.f : 0.f);
        A[ll * STRIDE + k * DIM + r] = v;
    }
    for (int e = tid; e < LPB * DIM; e += 1024) {
        int ll = e / DIM, r = e % DIM;
        int l = blk * LPB + ll;
        float v = (l < NUM_LAYERS) ? bs[(size_t)l * DIM + r] : 0.f;
        A[ll * STRIDE + 100 + r] = v;
    }

    const int wave = tid >> 6, lane = tid & 63;
    {
        const float* src = A;
        float* dst = B;
        for (int n = LPB / 2; n >= 1; n >>= 1) {   // 8,4,2,1
            __syncthreads();
            if (wave < n && lane <= DIM) compose_one(src, dst, wave, lane);
            const float* t = dst; dst = (float*)src; src = t;
        }
    }
    __syncthreads();                                // final chunk affine in A slot 0
    if (tid < 110) wsout[(size_t)blk * STRIDE + tid] = A[tid];

    // release: every thread fences its own stores, then one thread counts
    __threadfence();
    __syncthreads();
    if (tid == 0) s_last = atomicAdd(counter, 1u);
    __syncthreads();
    if (s_last != NBLK - 1) return;                 // not the last block

    // ---- phase 2 (last block only): fold 63 chunk affines ----
    __threadfence();                                // acquire side
    for (int e = tid; e < 64 * STRIDE; e += 1024) {
        int chunk = e / STRIDE, pos = e % STRIDE;
        float v;
        if (pos >= 110)        v = 0.f;
        else if (chunk < NBLK) v = __hip_atomic_load(&wsout[(size_t)chunk * STRIDE + pos],
                                                     __ATOMIC_RELAXED,
                                                     __HIP_MEMORY_SCOPE_AGENT);
        else v = (pos < 100 && (pos / 10 == pos % 10)) ? 1.f : 0.f;  // identity pad
        A[e] = v;
    }
    {
        const float* src = A;
        float* dst = B;
        for (int n = 32; n >= 1; n >>= 1) {         // 32,16,8,4,2,1
            __syncthreads();
            if (lane <= DIM)
                for (int c = wave; c < n; c += 16)
                    compose_one(src, dst, c, lane);
            const float* t = dst; dst = (float*)src; src = t;
        }
    }
    __syncthreads();                                // final in A slot 0 (col-major)
    if (tid < 110) {
        if (tid < 100) {
            int j = tid / DIM, r = tid % DIM;       // A[j*10+r] = M[r][j]
            aff[r * DIM + j] = A[tid];
        } else {
            aff[tid] = A[tid];                      // bias
        }
    }
}

// ---------------------------------------------------------------------------
// Apply: out = M x + c, LDS-staged so every global access is lane-contiguous.
// Tile = 512 rows (1280 float4 = 20 KB). Loads/stores: 5 coalesced float4 per
// thread (16 lines/wave-instr vs ~64 for the old 80B-strided pattern). Each
// thread then reads its own 20 contiguous floats (2 rows) from LDS; the
// stride-5-float4 b128 pattern covers all 32 banks per 8-lane phase ->
// conflict-free (verify via SQ_LDS_BANK_CONFLICT).
// ---------------------------------------------------------------------------
__global__ __launch_bounds__(256) void apply_affine(const float* __restrict__ x,
                                                    const float* __restrict__ aff,
                                                    float* __restrict__ out,
                                                    int nq4) {
    __shared__ float4 lds4[TILE_Q4];
    __shared__ float s[112];
    const int tid = threadIdx.x;
    if (tid < 112) s[tid] = (tid < 110) ? aff[tid] : 0.f;

    const int q0 = blockIdx.x * TILE_Q4;
    const float4* __restrict__ xin = (const float4*)x;
    float4* __restrict__ op = (float4*)out;

    #pragma unroll
    for (int i = 0; i < 5; ++i) {
        int q = q0 + i * 256 + tid;
        if (q < nq4) lds4[i * 256 + tid] = xin[q];
    }
    __syncthreads();

    // thread t owns floats [t*20, t*20+20) of the tile = rows {2t, 2t+1}
    if (q0 + 5 * tid + 5 <= nq4) {
        float xv[20];
        #pragma unroll
        for (int i = 0; i < 5; ++i) {
            float4 v = lds4[5 * tid + i];
            xv[4 * i + 0] = v.x; xv[4 * i + 1] = v.y;
            xv[4 * i + 2] = v.z; xv[4 * i + 3] = v.w;
        }
        float o[20];
        #pragma unroll
        for (int rr = 0; rr < 2; ++rr) {
            #pragma unroll
            for (int j = 0; j < DIM; ++j) {
                float acc = s[100 + j];
                #pragma unroll
                for (int k = 0; k < DIM; ++k)
                    acc += s[j * DIM + k] * xv[rr * DIM + k];
                o[rr * DIM + j] = acc;
            }
        }
        // same addresses this thread just read -> no sync needed in between
        #pragma unroll
        for (int i = 0; i < 5; ++i)
            lds4[5 * tid + i] = make_float4(o[4 * i + 0], o[4 * i + 1],
                                            o[4 * i + 2], o[4 * i + 3]);
    }
    __syncthreads();

    #pragma unroll
    for (int i = 0; i < 5; ++i) {
        int q = q0 + i * 256 + tid;
        if (q < nq4) op[q] = lds4[i * 256 + tid];
    }
}

extern "C" void kernel_launch(void* const* d_in, const int* in_sizes, int n_in,
                              void* d_out, int out_size, void* d_ws, size_t ws_size,
                              hipStream_t stream) {
    const float* x  = (const float*)d_in[0];   // [BATCH, 10]
    const float* Ws = (const float*)d_in[1];   // [1000, 10, 10]
    const float* bs = (const float*)d_in[2];   // [1000, 10]
    float* out = (float*)d_out;

    float* ws_chunks = (float*)d_ws;                       // NBLK * STRIDE floats
    float* ws_aff    = ws_chunks + NBLK * STRIDE;          // STRIDE floats
    unsigned int* ws_counter = (unsigned int*)(ws_aff + STRIDE);

    // zero the arrival counter (graph-capturable memset node, re-runs per replay)
    hipMemsetAsync(ws_counter, 0, sizeof(unsigned int), stream);

    compose_fused<<<NBLK, 1024, 0, stream>>>(Ws, bs, ws_chunks, ws_aff, ws_counter);

    const int nq4 = in_sizes[0] / 4;                       // in_sizes is in floats
    const int blocks = (nq4 + TILE_Q4 - 1) / TILE_Q4;
    apply_affine<<<blocks, 256, 0, stream>>>(x, ws_aff, out, nq4);
}